// Round 3
// 611.595 us; speedup vs baseline: 1.0512x; 1.0512x over previous
//
#include <hip/hip_runtime.h>

typedef short short8 __attribute__((ext_vector_type(8)));
typedef float float4v __attribute__((ext_vector_type(4)));
typedef __bf16 bf16x8 __attribute__((ext_vector_type(8)));

#define NA_ 100000
#define NS_ 50000
#define EAA_ 800000
#define ESS_ 400000
#define ESA_ 800000
#define POOLE_ (EAA_ + ESA_ + ESS_)  // 2,000,000
// concatenated node index space: [aa: 0..NA_), [sa: NA_..2*NA_), [ss: 2*NA_..2*NA_+NS_)
#define NNODES_ (NA_ + NA_ + NS_)   // 250000
#define SCAN_BLOCKS_ 62             // 62*4096 = 253952 >= NNODES_+1
#define NPAD_ (SCAN_BLOCKS_ * 4096)

static __device__ __forceinline__ float b2f(short s) {
  unsigned int u = ((unsigned int)(unsigned short)s) << 16;
  return __builtin_bit_cast(float, u);
}
static __device__ __forceinline__ short f2b(float f) {
  unsigned int u = __builtin_bit_cast(unsigned int, f);
  u = u + 0x7FFFu + ((u >> 16) & 1u);
  return (short)(u >> 16);
}

// ---------------- x fp32 -> bf16 (streaming) ----------------
__global__ void cvt_k(const float* __restrict__ x, short* __restrict__ y, int n8) {
  int i = blockIdx.x * 256 + threadIdx.x;
  if (i >= n8) return;
  const float* xp = x + (long)i * 8;
  float4v a0 = *(const float4v*)xp;
  float4v a1 = *(const float4v*)(xp + 4);
  short8 r;
#pragma unroll
  for (int j = 0; j < 4; ++j) {
    r[j] = f2b(a0[j]);
    r[4 + j] = f2b(a1[j]);
  }
  *(short8*)&y[(long)i * 8] = r;
}

// ---------------- all 4 W transposes in one kernel ----------------
__global__ void transpose_all_k(const float* __restrict__ W0, const float* __restrict__ W1,
                                const float* __restrict__ W2, const float* __restrict__ W3,
                                short* __restrict__ T0, short* __restrict__ T1,
                                short* __restrict__ T2, short* __restrict__ T3) {
  int tid = blockIdx.x * 256 + threadIdx.x;  // 4 * 32768
  int which = tid >> 15, r = tid & 32767;
  const float* W = which == 0 ? W0 : which == 1 ? W1 : which == 2 ? W2 : W3;
  short* T = which == 0 ? T0 : which == 1 ? T1 : which == 2 ? T2 : T3;
  int k = r >> 7, n = r & 127;
  T[n * 256 + k] = f2b(W[k * 128 + n]);
}

// ---------------- fused dual GEMM: C0,C1[M,128] = A[M,256] @ {Wt0,Wt1}^T ----------------
// A bf16 row-major; Wt0/Wt1 bf16 [128][256]. Block = 256 thr = 4 waves x 32 rows = 128 rows.
// LDS: 256 stacked N-rows (128 per weight) x 64-K-tile, stride 72 shorts (144B = 36 dw,
// 36 mod 32 = 4 -> 2-way bank alias = free, same pattern as proven LDN=136).
#define LDK 72
__global__ __launch_bounds__(256) void gemm2_k(const short* __restrict__ A,
                                               const short* __restrict__ Wt0,
                                               const short* __restrict__ Wt1,
                                               short* __restrict__ C0,
                                               short* __restrict__ C1, int M) {
  __shared__ short lds[256 * LDK];
  int tid = threadIdx.x;
  int wave = tid >> 6, lane = tid & 63;
  int l16 = lane & 15, lq = lane >> 4;
  int rowBase = blockIdx.x * 128 + wave * 32;

  float4v acc[2][16];
#pragma unroll
  for (int rt = 0; rt < 2; ++rt)
#pragma unroll
    for (int ct = 0; ct < 16; ++ct) acc[rt][ct] = (float4v){0.f, 0.f, 0.f, 0.f};

  for (int p = 0; p < 4; ++p) {
    int kp = p * 64;
    __syncthreads();
    // stage both weights' K-slice [*, kp:kp+64] into LDS (2048 short8 chunks)
    for (int idx = tid; idx < 2048; idx += 256) {
      int row = idx >> 3, c = idx & 7;  // row 0..255, c 0..7
      const short* Wsrc = (row < 128) ? &Wt0[row * 256] : &Wt1[(row - 128) * 256];
      *(short8*)&lds[row * LDK + c * 8] = *(const short8*)&Wsrc[kp + c * 8];
    }
    __syncthreads();
#pragma unroll
    for (int ks = 0; ks < 2; ++ks) {
      int k0 = kp + ks * 32;
      short8 af[2];
#pragma unroll
      for (int rt = 0; rt < 2; ++rt) {
        int row = rowBase + rt * 16 + l16;
        if (row >= M) row = M - 1;
        af[rt] = *(const short8*)&A[(long)row * 256 + k0 + lq * 8];
      }
#pragma unroll
      for (int ct = 0; ct < 16; ++ct) {
        short8 bfg = *(const short8*)&lds[(ct * 16 + l16) * LDK + ks * 32 + lq * 8];
#pragma unroll
        for (int rt = 0; rt < 2; ++rt) {
          acc[rt][ct] = __builtin_amdgcn_mfma_f32_16x16x32_bf16(
              __builtin_bit_cast(bf16x8, af[rt]), __builtin_bit_cast(bf16x8, bfg),
              acc[rt][ct], 0, 0, 0);
        }
      }
    }
  }
#pragma unroll
  for (int rt = 0; rt < 2; ++rt) {
    int r0 = rowBase + rt * 16 + lq * 4;
#pragma unroll
    for (int ct = 0; ct < 16; ++ct) {
      short* C = (ct < 8) ? C0 : C1;
      int col = (ct & 7) * 16 + l16;
#pragma unroll
      for (int r = 0; r < 4; ++r) {
        int row = r0 + r;
        if (row < M) C[(long)row * 128 + col] = f2b(acc[rt][ct][r]);
      }
    }
  }
}

// ---------------- CSR pass 1: count + per-edge rank (coalesced pos store) ----------------
__global__ void count_pos_k(const int* __restrict__ dst_aa, const int* __restrict__ sa_dst,
                            const int* __restrict__ dst_ss, int* __restrict__ cnt,
                            int* __restrict__ pos) {
  int i = blockIdx.x * 256 + threadIdx.x;
  int node;
  if (i < EAA_) node = dst_aa[i];
  else if (i < EAA_ + ESA_) node = NA_ + sa_dst[i - EAA_];
  else if (i < POOLE_) node = 2 * NA_ + dst_ss[i - EAA_ - ESA_];
  else return;
  pos[i] = atomicAdd(&cnt[node], 1);
}

// ---------------- scans ----------------
__global__ void scanA_k(const int* __restrict__ in, int* __restrict__ part,
                        int* __restrict__ bsums) {
  __shared__ int lds[256];
  int t = threadIdx.x, b = blockIdx.x;
  int base = b * 4096 + t * 16;
  int v[16];
  int run = 0;
#pragma unroll
  for (int j = 0; j < 16; ++j) {
    int x = (base + j < NNODES_) ? in[base + j] : 0;
    v[j] = run;
    run += x;
  }
  lds[t] = run;
  __syncthreads();
  int incl = run;
  for (int off = 1; off < 256; off <<= 1) {
    int add = (t >= off) ? lds[t - off] : 0;
    __syncthreads();
    lds[t] += add;
    incl = lds[t];
    __syncthreads();
  }
  int excl = incl - run;
#pragma unroll
  for (int j = 0; j < 16; ++j) part[base + j] = v[j] + excl;
  if (t == 255) bsums[b] = incl;
}
__global__ void scanB_k(int* __restrict__ bsums) {
  __shared__ int lds[256];
  int t = threadIdx.x;
  int v = (t < SCAN_BLOCKS_) ? bsums[t] : 0;
  lds[t] = v;
  __syncthreads();
  int incl = v;
  for (int off = 1; off < 256; off <<= 1) {
    int add = (t >= off) ? lds[t - off] : 0;
    __syncthreads();
    lds[t] += add;
    incl = lds[t];
    __syncthreads();
  }
  if (t < SCAN_BLOCKS_) bsums[t] = incl - v;
}
// scanC: finalize row_ptr + fused norms (dinv/invc from cnt)
__global__ void scanC_k(const int* __restrict__ part, const int* __restrict__ bsums,
                        const int* __restrict__ cnt, int* __restrict__ row_ptr,
                        float* __restrict__ dinv_aa, float* __restrict__ dinv_ss,
                        float* __restrict__ invc_sa) {
  int t = threadIdx.x, b = blockIdx.x;
  int base = b * 4096 + t * 16;
  int sb = bsums[b];
#pragma unroll
  for (int j = 0; j < 16; ++j) {
    int i = base + j;
    row_ptr[i] = part[i] + sb;
    if (i < NA_) dinv_aa[i] = rsqrtf((float)(cnt[i] + 1));
    else if (i < 2 * NA_) invc_sa[i - NA_] = 1.0f / fmaxf((float)cnt[i], 1.0f);
    else if (i < NNODES_) dinv_ss[i - 2 * NA_] = rsqrtf((float)(cnt[i] + 1));
  }
}

// ---------------- CSR pass 2: plain-store fill, 8B entries (src, weight) ----------------
__global__ void fill2_k(const int* __restrict__ src_aa, const int* __restrict__ dst_aa,
                        const int* __restrict__ sa_src, const int* __restrict__ sa_dst,
                        const int* __restrict__ src_ss, const int* __restrict__ dst_ss,
                        const int* __restrict__ row_ptr, const int* __restrict__ pos,
                        const float* __restrict__ dinv_aa, const float* __restrict__ dinv_ss,
                        const float* __restrict__ invc_sa, int2* __restrict__ pool) {
  int i = blockIdx.x * 256 + threadIdx.x;
  int s, node;
  float w;
  if (i < EAA_) {
    s = src_aa[i];
    int d = dst_aa[i];
    node = d;
    w = dinv_aa[s] * dinv_aa[d];
  } else if (i < EAA_ + ESA_) {
    int j = i - EAA_;
    s = sa_src[j];
    int d = sa_dst[j];
    node = NA_ + d;
    w = invc_sa[d];
  } else if (i < POOLE_) {
    int j = i - EAA_ - ESA_;
    s = src_ss[j];
    int d = dst_ss[j];
    node = 2 * NA_ + d;
    w = dinv_ss[s] * dinv_ss[d];
  } else
    return;
  pool[row_ptr[node] + pos[i]] = make_int2(s, __builtin_bit_cast(int, w));
}

// ---------------- gathers: 16 lanes/edge-row, short8 (16B) per lane ----------------
// Wave = 1 dst node. 4 groups of 16 lanes; group g walks edges jj+g, jj+4+g.
// Lane loads 8 contiguous bf16 channels (cb = (lane&15)*8) of its group's source row:
// one gather instruction covers 4 edges x 256B rows -> 4x fewer addr/load insts per edge
// than the old 64-lanes-per-edge short2 layout. Group partials combined once per node
// via 2-round shfl_xor(16/32); epilogue on group 0 (16 lanes x 32B stores).
static __device__ __forceinline__ void row_accum(const short* __restrict__ tab,
                                                 const int2* __restrict__ pool,
                                                 int r0, int r1, int g, int cb,
                                                 float* acc) {
  for (int jj = r0; jj < r1; jj += 8) {
    int e0 = jj + g, e1 = jj + 4 + g;
    int c0 = e0 < r1 ? e0 : r1 - 1;
    int c1 = e1 < r1 ? e1 : r1 - 1;
    int2 p0 = pool[c0];
    int2 p1 = pool[c1];
    float w0 = (e0 < r1) ? __builtin_bit_cast(float, p0.y) : 0.f;
    float w1 = (e1 < r1) ? __builtin_bit_cast(float, p1.y) : 0.f;
    short8 v0 = *(const short8*)&tab[(long)p0.x * 128 + cb];
    short8 v1 = *(const short8*)&tab[(long)p1.x * 128 + cb];
#pragma unroll
    for (int j = 0; j < 8; ++j) {
      acc[j] += b2f(v0[j]) * w0;
      acc[j] += b2f(v1[j]) * w1;
    }
  }
}

static __device__ __forceinline__ void xreduce8(float* acc) {
#pragma unroll
  for (int j = 0; j < 8; ++j) {
    acc[j] += __shfl_xor(acc[j], 16, 64);
    acc[j] += __shfl_xor(acc[j], 32, 64);
  }
}

__global__ __launch_bounds__(256) void gather_art16_k(
    const short* __restrict__ h_aa, const short* __restrict__ y_sl,
    const short* __restrict__ r_a, const int2* __restrict__ pool,
    const int* __restrict__ row_ptr, const float* __restrict__ dinv_aa,
    const float* __restrict__ b_aa, const float* __restrict__ b_sal,
    float* __restrict__ out) {
  int wave = threadIdx.x >> 6, lane = threadIdx.x & 63;
  int d = blockIdx.x * 4 + wave;
  if (d >= NA_) return;
  int l16 = lane & 15, g = lane >> 4;
  int cb = l16 * 8;

  float accA[8], accS[8];
#pragma unroll
  for (int j = 0; j < 8; ++j) accA[j] = accS[j] = 0.f;

  // GCN aa neighbors (weight = dinv[s]*dinv[d], precomputed)
  row_accum(h_aa, pool, row_ptr[d], row_ptr[d + 1], g, cb, accA);
  // SAGE sa neighbors (weight = invc[d], precomputed -> sum is already the mean)
  row_accum(y_sl, pool, row_ptr[NA_ + d], row_ptr[NA_ + d + 1], g, cb, accS);
  xreduce8(accA);
  xreduce8(accS);

  if (g == 0) {
    float dd = dinv_aa[d];
    float d2 = dd * dd;
    short8 hv = *(const short8*)&h_aa[(long)d * 128 + cb];
    short8 rv = *(const short8*)&r_a[(long)d * 128 + cb];
    float4v ba0 = *(const float4v*)&b_aa[cb];
    float4v ba1 = *(const float4v*)&b_aa[cb + 4];
    float4v bl0 = *(const float4v*)&b_sal[cb];
    float4v bl1 = *(const float4v*)&b_sal[cb + 4];
    float4v o0, o1;
#pragma unroll
    for (int j = 0; j < 4; ++j) {
      float t0 =
          0.5f * ((accA[j] + b2f(hv[j]) * d2 + ba0[j]) + (accS[j] + bl0[j] + b2f(rv[j])));
      float t1 = 0.5f * ((accA[4 + j] + b2f(hv[4 + j]) * d2 + ba1[j]) +
                         (accS[4 + j] + bl1[j] + b2f(rv[4 + j])));
      o0[j] = fmaxf(t0, 0.f);
      o1[j] = fmaxf(t1, 0.f);
    }
    *(float4v*)&out[(long)d * 128 + cb] = o0;
    *(float4v*)&out[(long)d * 128 + cb + 4] = o1;
  }
}

__global__ __launch_bounds__(256) void gather_soft16_k(
    const short* __restrict__ h_ss, const int2* __restrict__ pool,
    const int* __restrict__ row_ptr, const float* __restrict__ dinv_ss,
    const float* __restrict__ b_ss, float* __restrict__ out) {
  int wave = threadIdx.x >> 6, lane = threadIdx.x & 63;
  int d = blockIdx.x * 4 + wave;
  if (d >= NS_) return;
  int l16 = lane & 15, g = lane >> 4;
  int cb = l16 * 8;

  float acc[8];
#pragma unroll
  for (int j = 0; j < 8; ++j) acc[j] = 0.f;
  row_accum(h_ss, pool, row_ptr[2 * NA_ + d], row_ptr[2 * NA_ + d + 1], g, cb, acc);
  xreduce8(acc);

  if (g == 0) {
    float dd = dinv_ss[d];
    float d2 = dd * dd;
    short8 hv = *(const short8*)&h_ss[(long)d * 128 + cb];
    float4v bs0 = *(const float4v*)&b_ss[cb];
    float4v bs1 = *(const float4v*)&b_ss[cb + 4];
    float4v o0, o1;
#pragma unroll
    for (int j = 0; j < 4; ++j) {
      o0[j] = fmaxf(acc[j] + b2f(hv[j]) * d2 + bs0[j], 0.f);
      o1[j] = fmaxf(acc[4 + j] + b2f(hv[4 + j]) * d2 + bs1[j], 0.f);
    }
    *(float4v*)&out[(long)d * 128 + cb] = o0;
    *(float4v*)&out[(long)d * 128 + cb + 4] = o1;
  }
}

extern "C" void kernel_launch(void* const* d_in, const int* in_sizes, int n_in,
                              void* d_out, int out_size, void* d_ws, size_t ws_size,
                              hipStream_t stream) {
  const float* x_a = (const float*)d_in[0];
  const float* x_s = (const float*)d_in[1];
  const int* ei_aa = (const int*)d_in[2];
  const int* ei_ss = (const int*)d_in[3];
  const int* sa_src = (const int*)d_in[4];
  const int* sa_dst = (const int*)d_in[5];
  const float* W_aa = (const float*)d_in[6];
  const float* b_aa = (const float*)d_in[7];
  const float* W_ss = (const float*)d_in[8];
  const float* b_ss = (const float*)d_in[9];
  const float* W_sal = (const float*)d_in[10];
  const float* b_sal = (const float*)d_in[11];
  const float* W_sar = (const float*)d_in[12];

  const int* src_aa = ei_aa;
  const int* dst_aa = ei_aa + EAA_;
  const int* src_ss = ei_ss;
  const int* dst_ss = ei_ss + ESS_;

  // ---- workspace (~180 MB) ----
  char* base = (char*)d_ws;
  size_t off = 0;
  auto alloc = [&](size_t bytes) {
    void* p = base + off;
    off += (bytes + 511) & ~(size_t)511;
    return p;
  };
  short* xb_a = (short*)alloc((size_t)NA_ * 256 * 2);   // 51.2 MB
  short* xb_s = (short*)alloc((size_t)NS_ * 256 * 2);   // 25.6 MB
  short* h_aa = (short*)alloc((size_t)NA_ * 128 * 2);   // 25.6 MB
  short* h_ss = (short*)alloc((size_t)NS_ * 128 * 2);   // 12.8 MB
  short* y_sl = (short*)alloc((size_t)NS_ * 128 * 2);   // 12.8 MB
  short* r_a = (short*)alloc((size_t)NA_ * 128 * 2);    // 25.6 MB
  int2* pool = (int2*)alloc((size_t)POOLE_ * 8);        // 16 MB
  int* pos = (int*)alloc((size_t)POOLE_ * 4);           // 8 MB
  int* cnt_all = (int*)alloc((size_t)NNODES_ * 4);
  int* part = (int*)alloc((size_t)NPAD_ * 4);
  int* row_ptr = (int*)alloc((size_t)NPAD_ * 4);
  int* bsums = (int*)alloc(256 * 4);
  float* dinv_aa = (float*)alloc((size_t)NA_ * 4);
  float* dinv_ss = (float*)alloc((size_t)NS_ * 4);
  float* invc_sa = (float*)alloc((size_t)NA_ * 4);
  short* Wt_aa = (short*)alloc(128 * 256 * 2);
  short* Wt_ss = (short*)alloc(128 * 256 * 2);
  short* Wt_sal = (short*)alloc(128 * 256 * 2);
  short* Wt_sar = (short*)alloc(128 * 256 * 2);

  float* out_art = (float*)d_out;
  float* out_soft = (float*)d_out + (size_t)NA_ * 128;

  // ---- CSR build (two-pass, atomic-free fill) ----
  hipMemsetAsync(cnt_all, 0, (size_t)NNODES_ * 4, stream);
  count_pos_k<<<(POOLE_ + 255) / 256, 256, 0, stream>>>(dst_aa, sa_dst, dst_ss, cnt_all, pos);
  scanA_k<<<SCAN_BLOCKS_, 256, 0, stream>>>(cnt_all, part, bsums);
  scanB_k<<<1, 256, 0, stream>>>(bsums);
  scanC_k<<<SCAN_BLOCKS_, 256, 0, stream>>>(part, bsums, cnt_all, row_ptr, dinv_aa, dinv_ss,
                                            invc_sa);
  fill2_k<<<(POOLE_ + 255) / 256, 256, 0, stream>>>(src_aa, dst_aa, sa_src, sa_dst, src_ss,
                                                    dst_ss, row_ptr, pos, dinv_aa, dinv_ss,
                                                    invc_sa, pool);

  // ---- weights + x conversion + fused GEMMs ----
  transpose_all_k<<<512, 256, 0, stream>>>(W_aa, W_ss, W_sal, W_sar, Wt_aa, Wt_ss, Wt_sal,
                                           Wt_sar);
  cvt_k<<<(NA_ * 32 + 255) / 256, 256, 0, stream>>>(x_a, xb_a, NA_ * 32);
  cvt_k<<<(NS_ * 32 + 255) / 256, 256, 0, stream>>>(x_s, xb_s, NS_ * 32);
  gemm2_k<<<(NA_ + 127) / 128, 256, 0, stream>>>(xb_a, Wt_aa, Wt_sar, h_aa, r_a, NA_);
  gemm2_k<<<(NS_ + 127) / 128, 256, 0, stream>>>(xb_s, Wt_ss, Wt_sal, h_ss, y_sl, NS_);

  // ---- gathers (new 16-lane/short8 layout, two launches) ----
  gather_art16_k<<<(NA_ + 3) / 4, 256, 0, stream>>>(h_aa, y_sl, r_a, pool, row_ptr, dinv_aa,
                                                    b_aa, b_sal, out_art);
  gather_soft16_k<<<(NS_ + 3) / 4, 256, 0, stream>>>(h_ss, pool, row_ptr, dinv_ss, b_ss,
                                                     out_soft);
}

// Round 6
// 607.528 us; speedup vs baseline: 1.0582x; 1.0067x over previous
//
#include <hip/hip_runtime.h>

typedef short short8 __attribute__((ext_vector_type(8)));
typedef float float4v __attribute__((ext_vector_type(4)));
typedef __bf16 bf16x8 __attribute__((ext_vector_type(8)));

#define NA_ 100000
#define NS_ 50000
#define EAA_ 800000
#define ESS_ 400000
#define ESA_ 800000
#define POOLE_ (EAA_ + ESA_ + ESS_)  // 2,000,000
// concatenated node index space: [aa: 0..NA_), [sa: NA_..2*NA_), [ss: 2*NA_..2*NA_+NS_)
#define NNODES_ (NA_ + NA_ + NS_)   // 250000
#define SCAN_BLOCKS_ 62             // 62*4096 = 253952 >= NNODES_+1
#define NPAD_ (SCAN_BLOCKS_ * 4096)

static __device__ __forceinline__ float b2f(short s) {
  unsigned int u = ((unsigned int)(unsigned short)s) << 16;
  return __builtin_bit_cast(float, u);
}
static __device__ __forceinline__ short f2b(float f) {
  unsigned int u = __builtin_bit_cast(unsigned int, f);
  u = u + 0x7FFFu + ((u >> 16) & 1u);
  return (short)(u >> 16);
}

// ---------------- x fp32 -> bf16 (streaming) ----------------
__global__ void cvt_k(const float* __restrict__ x, short* __restrict__ y, int n8) {
  int i = blockIdx.x * 256 + threadIdx.x;
  if (i >= n8) return;
  const float* xp = x + (long)i * 8;
  float4v a0 = *(const float4v*)xp;
  float4v a1 = *(const float4v*)(xp + 4);
  short8 r;
#pragma unroll
  for (int j = 0; j < 4; ++j) {
    r[j] = f2b(a0[j]);
    r[4 + j] = f2b(a1[j]);
  }
  *(short8*)&y[(long)i * 8] = r;
}

// ---------------- all 4 W transposes in one kernel ----------------
__global__ void transpose_all_k(const float* __restrict__ W0, const float* __restrict__ W1,
                                const float* __restrict__ W2, const float* __restrict__ W3,
                                short* __restrict__ T0, short* __restrict__ T1,
                                short* __restrict__ T2, short* __restrict__ T3) {
  int tid = blockIdx.x * 256 + threadIdx.x;  // 4 * 32768
  int which = tid >> 15, r = tid & 32767;
  const float* W = which == 0 ? W0 : which == 1 ? W1 : which == 2 ? W2 : W3;
  short* T = which == 0 ? T0 : which == 1 ? T1 : which == 2 ? T2 : T3;
  int k = r >> 7, n = r & 127;
  T[n * 256 + k] = f2b(W[k * 128 + n]);
}

// ---------------- fused dual GEMM: C0,C1[M,128] = A[M,256] @ {Wt0,Wt1}^T ----------------
// A bf16 row-major; Wt0/Wt1 bf16 [128][256]. Block = 256 thr = 4 waves x 32 rows = 128 rows.
// LDS: 256 stacked N-rows (128 per weight) x 64-K-tile, stride 72 shorts (144B = 36 dw,
// 36 mod 32 = 4 -> 2-way bank alias = free, same pattern as proven LDN=136).
#define LDK 72
__global__ __launch_bounds__(256) void gemm2_k(const short* __restrict__ A,
                                               const short* __restrict__ Wt0,
                                               const short* __restrict__ Wt1,
                                               short* __restrict__ C0,
                                               short* __restrict__ C1, int M) {
  __shared__ short lds[256 * LDK];
  int tid = threadIdx.x;
  int wave = tid >> 6, lane = tid & 63;
  int l16 = lane & 15, lq = lane >> 4;
  int rowBase = blockIdx.x * 128 + wave * 32;

  float4v acc[2][16];
#pragma unroll
  for (int rt = 0; rt < 2; ++rt)
#pragma unroll
    for (int ct = 0; ct < 16; ++ct) acc[rt][ct] = (float4v){0.f, 0.f, 0.f, 0.f};

  for (int p = 0; p < 4; ++p) {
    int kp = p * 64;
    __syncthreads();
    // stage both weights' K-slice [*, kp:kp+64] into LDS (2048 short8 chunks)
    for (int idx = tid; idx < 2048; idx += 256) {
      int row = idx >> 3, c = idx & 7;  // row 0..255, c 0..7
      const short* Wsrc = (row < 128) ? &Wt0[row * 256] : &Wt1[(row - 128) * 256];
      *(short8*)&lds[row * LDK + c * 8] = *(const short8*)&Wsrc[kp + c * 8];
    }
    __syncthreads();
#pragma unroll
    for (int ks = 0; ks < 2; ++ks) {
      int k0 = kp + ks * 32;
      short8 af[2];
#pragma unroll
      for (int rt = 0; rt < 2; ++rt) {
        int row = rowBase + rt * 16 + l16;
        if (row >= M) row = M - 1;
        af[rt] = *(const short8*)&A[(long)row * 256 + k0 + lq * 8];
      }
#pragma unroll
      for (int ct = 0; ct < 16; ++ct) {
        short8 bfg = *(const short8*)&lds[(ct * 16 + l16) * LDK + ks * 32 + lq * 8];
#pragma unroll
        for (int rt = 0; rt < 2; ++rt) {
          acc[rt][ct] = __builtin_amdgcn_mfma_f32_16x16x32_bf16(
              __builtin_bit_cast(bf16x8, af[rt]), __builtin_bit_cast(bf16x8, bfg),
              acc[rt][ct], 0, 0, 0);
        }
      }
    }
  }
#pragma unroll
  for (int rt = 0; rt < 2; ++rt) {
    int r0 = rowBase + rt * 16 + lq * 4;
#pragma unroll
    for (int ct = 0; ct < 16; ++ct) {
      short* C = (ct < 8) ? C0 : C1;
      int col = (ct & 7) * 16 + l16;
#pragma unroll
      for (int r = 0; r < 4; ++r) {
        int row = r0 + r;
        if (row < M) C[(long)row * 128 + col] = f2b(acc[rt][ct][r]);
      }
    }
  }
}

// ---------------- CSR pass 1: count + per-edge rank (coalesced pos store) ----------------
__global__ void count_pos_k(const int* __restrict__ dst_aa, const int* __restrict__ sa_dst,
                            const int* __restrict__ dst_ss, int* __restrict__ cnt,
                            int* __restrict__ pos) {
  int i = blockIdx.x * 256 + threadIdx.x;
  int node;
  if (i < EAA_) node = dst_aa[i];
  else if (i < EAA_ + ESA_) node = NA_ + sa_dst[i - EAA_];
  else if (i < POOLE_) node = 2 * NA_ + dst_ss[i - EAA_ - ESA_];
  else return;
  pos[i] = atomicAdd(&cnt[node], 1);
}

// ---------------- scans ----------------
__global__ void scanA_k(const int* __restrict__ in, int* __restrict__ part,
                        int* __restrict__ bsums) {
  __shared__ int lds[256];
  int t = threadIdx.x, b = blockIdx.x;
  int base = b * 4096 + t * 16;
  int v[16];
  int run = 0;
#pragma unroll
  for (int j = 0; j < 16; ++j) {
    int x = (base + j < NNODES_) ? in[base + j] : 0;
    v[j] = run;
    run += x;
  }
  lds[t] = run;
  __syncthreads();
  int incl = run;
  for (int off = 1; off < 256; off <<= 1) {
    int add = (t >= off) ? lds[t - off] : 0;
    __syncthreads();
    lds[t] += add;
    incl = lds[t];
    __syncthreads();
  }
  int excl = incl - run;
#pragma unroll
  for (int j = 0; j < 16; ++j) part[base + j] = v[j] + excl;
  if (t == 255) bsums[b] = incl;
}
__global__ void scanB_k(int* __restrict__ bsums) {
  __shared__ int lds[256];
  int t = threadIdx.x;
  int v = (t < SCAN_BLOCKS_) ? bsums[t] : 0;
  lds[t] = v;
  __syncthreads();
  int incl = v;
  for (int off = 1; off < 256; off <<= 1) {
    int add = (t >= off) ? lds[t - off] : 0;
    __syncthreads();
    lds[t] += add;
    incl = lds[t];
    __syncthreads();
  }
  if (t < SCAN_BLOCKS_) bsums[t] = incl - v;
}
// scanC: finalize row_ptr + fused norms (dinv/invc from cnt)
__global__ void scanC_k(const int* __restrict__ part, const int* __restrict__ bsums,
                        const int* __restrict__ cnt, int* __restrict__ row_ptr,
                        float* __restrict__ dinv_aa, float* __restrict__ dinv_ss,
                        float* __restrict__ invc_sa) {
  int t = threadIdx.x, b = blockIdx.x;
  int base = b * 4096 + t * 16;
  int sb = bsums[b];
#pragma unroll
  for (int j = 0; j < 16; ++j) {
    int i = base + j;
    row_ptr[i] = part[i] + sb;
    if (i < NA_) dinv_aa[i] = rsqrtf((float)(cnt[i] + 1));
    else if (i < 2 * NA_) invc_sa[i - NA_] = 1.0f / fmaxf((float)cnt[i], 1.0f);
    else if (i < NNODES_) dinv_ss[i - 2 * NA_] = rsqrtf((float)(cnt[i] + 1));
  }
}

// ---------------- CSR pass 2: plain-store fill, 8B entries (src, weight) ----------------
__global__ void fill2_k(const int* __restrict__ src_aa, const int* __restrict__ dst_aa,
                        const int* __restrict__ sa_src, const int* __restrict__ sa_dst,
                        const int* __restrict__ src_ss, const int* __restrict__ dst_ss,
                        const int* __restrict__ row_ptr, const int* __restrict__ pos,
                        const float* __restrict__ dinv_aa, const float* __restrict__ dinv_ss,
                        const float* __restrict__ invc_sa, int2* __restrict__ pool) {
  int i = blockIdx.x * 256 + threadIdx.x;
  int s, node;
  float w;
  if (i < EAA_) {
    s = src_aa[i];
    int d = dst_aa[i];
    node = d;
    w = dinv_aa[s] * dinv_aa[d];
  } else if (i < EAA_ + ESA_) {
    int j = i - EAA_;
    s = sa_src[j];
    int d = sa_dst[j];
    node = NA_ + d;
    w = invc_sa[d];
  } else if (i < POOLE_) {
    int j = i - EAA_ - ESA_;
    s = src_ss[j];
    int d = dst_ss[j];
    node = 2 * NA_ + d;
    w = dinv_ss[s] * dinv_ss[d];
  } else
    return;
  pool[row_ptr[node] + pos[i]] = make_int2(s, __builtin_bit_cast(int, w));
}

// ---------------- gathers: 16 lanes/edge-row, short8 (16B) per lane ----------------
// Wave = 1 dst node. 4 groups of 16 lanes; group g walks edges jj+g, jj+4+g.
// Lane loads 8 contiguous bf16 channels (cb = (lane&15)*8) of its group's source row.
// Split loop: full 8-edge chunks run MASKLESS (only the final chunk of a row can be
// partial); one masked tail chunk (identical to the proven round-3 body) handles the
// remainder. Semantics identical to round 3 — no CSR padding, no pool zeroing.
// Group partials combined via 2-round shfl_xor(16/32); epilogue on group 0.
static __device__ __forceinline__ void row_accum(const short* __restrict__ tab,
                                                 const int2* __restrict__ pool,
                                                 int r0, int r1, int g, int cb,
                                                 float* acc) {
  int n = r1 - r0;
  int r1f = r0 + (n & ~7);  // end of full (maskless) chunks
  for (int jj = r0; jj < r1f; jj += 8) {
    int2 p0 = pool[jj + g];
    int2 p1 = pool[jj + 4 + g];
    float w0 = __builtin_bit_cast(float, p0.y);
    float w1 = __builtin_bit_cast(float, p1.y);
    short8 v0 = *(const short8*)&tab[(long)p0.x * 128 + cb];
    short8 v1 = *(const short8*)&tab[(long)p1.x * 128 + cb];
#pragma unroll
    for (int j = 0; j < 8; ++j) {
      acc[j] += b2f(v0[j]) * w0;
      acc[j] += b2f(v1[j]) * w1;
    }
  }
  if (r1f < r1) {  // single masked tail chunk (round-3 body)
    int e0 = r1f + g, e1 = r1f + 4 + g;
    int c0 = e0 < r1 ? e0 : r1 - 1;
    int c1 = e1 < r1 ? e1 : r1 - 1;
    int2 p0 = pool[c0];
    int2 p1 = pool[c1];
    float w0 = (e0 < r1) ? __builtin_bit_cast(float, p0.y) : 0.f;
    float w1 = (e1 < r1) ? __builtin_bit_cast(float, p1.y) : 0.f;
    short8 v0 = *(const short8*)&tab[(long)p0.x * 128 + cb];
    short8 v1 = *(const short8*)&tab[(long)p1.x * 128 + cb];
#pragma unroll
    for (int j = 0; j < 8; ++j) {
      acc[j] += b2f(v0[j]) * w0;
      acc[j] += b2f(v1[j]) * w1;
    }
  }
}

static __device__ __forceinline__ void xreduce8(float* acc) {
#pragma unroll
  for (int j = 0; j < 8; ++j) {
    acc[j] += __shfl_xor(acc[j], 16, 64);
    acc[j] += __shfl_xor(acc[j], 32, 64);
  }
}

__global__ __launch_bounds__(256) void gather_art16_k(
    const short* __restrict__ h_aa, const short* __restrict__ y_sl,
    const short* __restrict__ r_a, const int2* __restrict__ pool,
    const int* __restrict__ row_ptr, const float* __restrict__ dinv_aa,
    const float* __restrict__ b_aa, const float* __restrict__ b_sal,
    float* __restrict__ out) {
  int wave = threadIdx.x >> 6, lane = threadIdx.x & 63;
  int d = blockIdx.x * 4 + wave;
  if (d >= NA_) return;
  int l16 = lane & 15, g = lane >> 4;
  int cb = l16 * 8;

  float accA[8], accS[8];
#pragma unroll
  for (int j = 0; j < 8; ++j) accA[j] = accS[j] = 0.f;

  // GCN aa neighbors (weight = dinv[s]*dinv[d], precomputed)
  row_accum(h_aa, pool, row_ptr[d], row_ptr[d + 1], g, cb, accA);
  // SAGE sa neighbors (weight = invc[d], precomputed -> sum is already the mean)
  row_accum(y_sl, pool, row_ptr[NA_ + d], row_ptr[NA_ + d + 1], g, cb, accS);
  xreduce8(accA);
  xreduce8(accS);

  if (g == 0) {
    float dd = dinv_aa[d];
    float d2 = dd * dd;
    short8 hv = *(const short8*)&h_aa[(long)d * 128 + cb];
    short8 rv = *(const short8*)&r_a[(long)d * 128 + cb];
    float4v ba0 = *(const float4v*)&b_aa[cb];
    float4v ba1 = *(const float4v*)&b_aa[cb + 4];
    float4v bl0 = *(const float4v*)&b_sal[cb];
    float4v bl1 = *(const float4v*)&b_sal[cb + 4];
    float4v o0, o1;
#pragma unroll
    for (int j = 0; j < 4; ++j) {
      float t0 =
          0.5f * ((accA[j] + b2f(hv[j]) * d2 + ba0[j]) + (accS[j] + bl0[j] + b2f(rv[j])));
      float t1 = 0.5f * ((accA[4 + j] + b2f(hv[4 + j]) * d2 + ba1[j]) +
                         (accS[4 + j] + bl1[j] + b2f(rv[4 + j])));
      o0[j] = fmaxf(t0, 0.f);
      o1[j] = fmaxf(t1, 0.f);
    }
    *(float4v*)&out[(long)d * 128 + cb] = o0;
    *(float4v*)&out[(long)d * 128 + cb + 4] = o1;
  }
}

__global__ __launch_bounds__(256) void gather_soft16_k(
    const short* __restrict__ h_ss, const int2* __restrict__ pool,
    const int* __restrict__ row_ptr, const float* __restrict__ dinv_ss,
    const float* __restrict__ b_ss, float* __restrict__ out) {
  int wave = threadIdx.x >> 6, lane = threadIdx.x & 63;
  int d = blockIdx.x * 4 + wave;
  if (d >= NS_) return;
  int l16 = lane & 15, g = lane >> 4;
  int cb = l16 * 8;

  float acc[8];
#pragma unroll
  for (int j = 0; j < 8; ++j) acc[j] = 0.f;
  row_accum(h_ss, pool, row_ptr[2 * NA_ + d], row_ptr[2 * NA_ + d + 1], g, cb, acc);
  xreduce8(acc);

  if (g == 0) {
    float dd = dinv_ss[d];
    float d2 = dd * dd;
    short8 hv = *(const short8*)&h_ss[(long)d * 128 + cb];
    float4v bs0 = *(const float4v*)&b_ss[cb];
    float4v bs1 = *(const float4v*)&b_ss[cb + 4];
    float4v o0, o1;
#pragma unroll
    for (int j = 0; j < 4; ++j) {
      o0[j] = fmaxf(acc[j] + b2f(hv[j]) * d2 + bs0[j], 0.f);
      o1[j] = fmaxf(acc[4 + j] + b2f(hv[4 + j]) * d2 + bs1[j], 0.f);
    }
    *(float4v*)&out[(long)d * 128 + cb] = o0;
    *(float4v*)&out[(long)d * 128 + cb + 4] = o1;
  }
}

extern "C" void kernel_launch(void* const* d_in, const int* in_sizes, int n_in,
                              void* d_out, int out_size, void* d_ws, size_t ws_size,
                              hipStream_t stream) {
  const float* x_a = (const float*)d_in[0];
  const float* x_s = (const float*)d_in[1];
  const int* ei_aa = (const int*)d_in[2];
  const int* ei_ss = (const int*)d_in[3];
  const int* sa_src = (const int*)d_in[4];
  const int* sa_dst = (const int*)d_in[5];
  const float* W_aa = (const float*)d_in[6];
  const float* b_aa = (const float*)d_in[7];
  const float* W_ss = (const float*)d_in[8];
  const float* b_ss = (const float*)d_in[9];
  const float* W_sal = (const float*)d_in[10];
  const float* b_sal = (const float*)d_in[11];
  const float* W_sar = (const float*)d_in[12];

  const int* src_aa = ei_aa;
  const int* dst_aa = ei_aa + EAA_;
  const int* src_ss = ei_ss;
  const int* dst_ss = ei_ss + ESS_;

  // ---- workspace (~180 MB, identical layout to the proven round-3 run) ----
  char* base = (char*)d_ws;
  size_t off = 0;
  auto alloc = [&](size_t bytes) {
    void* p = base + off;
    off += (bytes + 511) & ~(size_t)511;
    return p;
  };
  short* xb_a = (short*)alloc((size_t)NA_ * 256 * 2);   // 51.2 MB
  short* xb_s = (short*)alloc((size_t)NS_ * 256 * 2);   // 25.6 MB
  short* h_aa = (short*)alloc((size_t)NA_ * 128 * 2);   // 25.6 MB
  short* h_ss = (short*)alloc((size_t)NS_ * 128 * 2);   // 12.8 MB
  short* y_sl = (short*)alloc((size_t)NS_ * 128 * 2);   // 12.8 MB
  short* r_a = (short*)alloc((size_t)NA_ * 128 * 2);    // 25.6 MB
  int2* pool = (int2*)alloc((size_t)POOLE_ * 8);        // 16 MB
  int* pos = (int*)alloc((size_t)POOLE_ * 4);           // 8 MB
  int* cnt_all = (int*)alloc((size_t)NNODES_ * 4);
  int* part = (int*)alloc((size_t)NPAD_ * 4);
  int* row_ptr = (int*)alloc((size_t)NPAD_ * 4);
  int* bsums = (int*)alloc(256 * 4);
  float* dinv_aa = (float*)alloc((size_t)NA_ * 4);
  float* dinv_ss = (float*)alloc((size_t)NS_ * 4);
  float* invc_sa = (float*)alloc((size_t)NA_ * 4);
  short* Wt_aa = (short*)alloc(128 * 256 * 2);
  short* Wt_ss = (short*)alloc(128 * 256 * 2);
  short* Wt_sal = (short*)alloc(128 * 256 * 2);
  short* Wt_sar = (short*)alloc(128 * 256 * 2);

  float* out_art = (float*)d_out;
  float* out_soft = (float*)d_out + (size_t)NA_ * 128;

  // ---- CSR build (two-pass, atomic-free fill) ----
  hipMemsetAsync(cnt_all, 0, (size_t)NNODES_ * 4, stream);
  count_pos_k<<<(POOLE_ + 255) / 256, 256, 0, stream>>>(dst_aa, sa_dst, dst_ss, cnt_all, pos);
  scanA_k<<<SCAN_BLOCKS_, 256, 0, stream>>>(cnt_all, part, bsums);
  scanB_k<<<1, 256, 0, stream>>>(bsums);
  scanC_k<<<SCAN_BLOCKS_, 256, 0, stream>>>(part, bsums, cnt_all, row_ptr, dinv_aa, dinv_ss,
                                            invc_sa);
  fill2_k<<<(POOLE_ + 255) / 256, 256, 0, stream>>>(src_aa, dst_aa, sa_src, sa_dst, src_ss,
                                                    dst_ss, row_ptr, pos, dinv_aa, dinv_ss,
                                                    invc_sa, pool);

  // ---- weights + x conversion + fused GEMMs ----
  transpose_all_k<<<512, 256, 0, stream>>>(W_aa, W_ss, W_sal, W_sar, Wt_aa, Wt_ss, Wt_sal,
                                           Wt_sar);
  cvt_k<<<(NA_ * 32 + 255) / 256, 256, 0, stream>>>(x_a, xb_a, NA_ * 32);
  cvt_k<<<(NS_ * 32 + 255) / 256, 256, 0, stream>>>(x_s, xb_s, NS_ * 32);
  gemm2_k<<<(NA_ + 127) / 128, 256, 0, stream>>>(xb_a, Wt_aa, Wt_sar, h_aa, r_a, NA_);
  gemm2_k<<<(NS_ + 127) / 128, 256, 0, stream>>>(xb_s, Wt_ss, Wt_sal, h_ss, y_sl, NS_);

  // ---- gathers (16-lane/short8 layout, maskless full chunks + masked tail) ----
  gather_art16_k<<<(NA_ + 3) / 4, 256, 0, stream>>>(h_aa, y_sl, r_a, pool, row_ptr, dinv_aa,
                                                    b_aa, b_sal, out_art);
  gather_soft16_k<<<(NS_ + 3) / 4, 256, 0, stream>>>(h_ss, pool, row_ptr, dinv_ss, b_ss,
                                                     out_soft);
}

// Round 7
// 594.877 us; speedup vs baseline: 1.0807x; 1.0213x over previous
//
#include <hip/hip_runtime.h>

typedef short short8 __attribute__((ext_vector_type(8)));
typedef float float4v __attribute__((ext_vector_type(4)));
typedef __bf16 bf16x8 __attribute__((ext_vector_type(8)));

#define NA_ 100000
#define NS_ 50000
#define EAA_ 800000
#define ESS_ 400000
#define ESA_ 800000
#define POOLE_ (EAA_ + ESA_ + ESS_)  // 2,000,000
// concatenated node index space: [aa: 0..NA_), [sa: NA_..2*NA_), [ss: 2*NA_..2*NA_+NS_)
#define NNODES_ (NA_ + NA_ + NS_)   // 250000
#define SCAN_BLOCKS_ 62             // 62*4096 = 253952 >= NNODES_+1
#define NPAD_ (SCAN_BLOCKS_ * 4096)

// prep_k block-range layout (all 256-thread, LDS-free)
#define CPB_ 7813    // count_pos blocks: 7813*256 = 2000128 >= POOLE_
#define CVA_ 12500   // cvt x_article: 12500*256 = NA_*32 exactly
#define CVS_ 6250    // cvt x_software: 6250*256 = NS_*32 exactly
#define TRB_ 512     // transpose: 512*256 = 4*32768 exactly
#define PREPB_ (CPB_ + CVA_ + CVS_ + TRB_)  // 27075

static __device__ __forceinline__ float b2f(short s) {
  unsigned int u = ((unsigned int)(unsigned short)s) << 16;
  return __builtin_bit_cast(float, u);
}
static __device__ __forceinline__ short f2b(float f) {
  unsigned int u = __builtin_bit_cast(unsigned int, f);
  u = u + 0x7FFFu + ((u >> 16) & 1u);
  return (short)(u >> 16);
}

// bf16 convert: 8 floats -> 8 shorts at element index i*8
static __device__ __forceinline__ void cvt_body(const float* __restrict__ x,
                                                short* __restrict__ y, int i) {
  const float* xp = x + (long)i * 8;
  float4v a0 = *(const float4v*)xp;
  float4v a1 = *(const float4v*)(xp + 4);
  short8 r;
#pragma unroll
  for (int j = 0; j < 4; ++j) {
    r[j] = f2b(a0[j]);
    r[4 + j] = f2b(a1[j]);
  }
  *(short8*)&y[(long)i * 8] = r;
}

// ---------------- fused prep: count_pos + cvt_a + cvt_s + 4x W transpose ----------------
// count_pos blocks are atomic-latency/throughput bound (VALU ~0.6%, HBM ~11% measured);
// cvt/transpose blocks are pure streaming. Co-dispatching them overlaps the ~86us of
// atomic time with ~40us of streaming time on otherwise-idle CUs.
__global__ __launch_bounds__(256) void prep_k(
    const int* __restrict__ dst_aa, const int* __restrict__ sa_dst,
    const int* __restrict__ dst_ss, int* __restrict__ cnt, int* __restrict__ pos,
    const float* __restrict__ x_a, short* __restrict__ xb_a,
    const float* __restrict__ x_s, short* __restrict__ xb_s,
    const float* __restrict__ W0, const float* __restrict__ W1,
    const float* __restrict__ W2, const float* __restrict__ W3,
    short* __restrict__ T0, short* __restrict__ T1,
    short* __restrict__ T2, short* __restrict__ T3) {
  int b = blockIdx.x, t = threadIdx.x;
  if (b < CPB_) {
    int i = b * 256 + t;
    if (i >= POOLE_) return;
    int node;
    if (i < EAA_) node = dst_aa[i];
    else if (i < EAA_ + ESA_) node = NA_ + sa_dst[i - EAA_];
    else node = 2 * NA_ + dst_ss[i - EAA_ - ESA_];
    pos[i] = atomicAdd(&cnt[node], 1);
  } else if (b < CPB_ + CVA_) {
    cvt_body(x_a, xb_a, (b - CPB_) * 256 + t);
  } else if (b < CPB_ + CVA_ + CVS_) {
    cvt_body(x_s, xb_s, (b - CPB_ - CVA_) * 256 + t);
  } else {
    int tid = (b - CPB_ - CVA_ - CVS_) * 256 + t;  // 0 .. 4*32768
    int which = tid >> 15, r = tid & 32767;
    const float* W = which == 0 ? W0 : which == 1 ? W1 : which == 2 ? W2 : W3;
    short* T = which == 0 ? T0 : which == 1 ? T1 : which == 2 ? T2 : T3;
    int k = r >> 7, n = r & 127;
    T[n * 256 + k] = f2b(W[k * 128 + n]);
  }
}

// ---------------- fused dual GEMM: C0,C1[M,128] = A[M,256] @ {Wt0,Wt1}^T ----------------
// A bf16 row-major; Wt0/Wt1 bf16 [128][256]. Block = 256 thr = 4 waves x 32 rows = 128 rows.
// LDS: 256 stacked N-rows (128 per weight) x 64-K-tile, stride 72 shorts (144B = 36 dw,
// 36 mod 32 = 4 -> 2-way bank alias = free, same pattern as proven LDN=136).
#define LDK 72
__global__ __launch_bounds__(256) void gemm2_k(const short* __restrict__ A,
                                               const short* __restrict__ Wt0,
                                               const short* __restrict__ Wt1,
                                               short* __restrict__ C0,
                                               short* __restrict__ C1, int M) {
  __shared__ short lds[256 * LDK];
  int tid = threadIdx.x;
  int wave = tid >> 6, lane = tid & 63;
  int l16 = lane & 15, lq = lane >> 4;
  int rowBase = blockIdx.x * 128 + wave * 32;

  float4v acc[2][16];
#pragma unroll
  for (int rt = 0; rt < 2; ++rt)
#pragma unroll
    for (int ct = 0; ct < 16; ++ct) acc[rt][ct] = (float4v){0.f, 0.f, 0.f, 0.f};

  for (int p = 0; p < 4; ++p) {
    int kp = p * 64;
    __syncthreads();
    // stage both weights' K-slice [*, kp:kp+64] into LDS (2048 short8 chunks)
    for (int idx = tid; idx < 2048; idx += 256) {
      int row = idx >> 3, c = idx & 7;  // row 0..255, c 0..7
      const short* Wsrc = (row < 128) ? &Wt0[row * 256] : &Wt1[(row - 128) * 256];
      *(short8*)&lds[row * LDK + c * 8] = *(const short8*)&Wsrc[kp + c * 8];
    }
    __syncthreads();
#pragma unroll
    for (int ks = 0; ks < 2; ++ks) {
      int k0 = kp + ks * 32;
      short8 af[2];
#pragma unroll
      for (int rt = 0; rt < 2; ++rt) {
        int row = rowBase + rt * 16 + l16;
        if (row >= M) row = M - 1;
        af[rt] = *(const short8*)&A[(long)row * 256 + k0 + lq * 8];
      }
#pragma unroll
      for (int ct = 0; ct < 16; ++ct) {
        short8 bfg = *(const short8*)&lds[(ct * 16 + l16) * LDK + ks * 32 + lq * 8];
#pragma unroll
        for (int rt = 0; rt < 2; ++rt) {
          acc[rt][ct] = __builtin_amdgcn_mfma_f32_16x16x32_bf16(
              __builtin_bit_cast(bf16x8, af[rt]), __builtin_bit_cast(bf16x8, bfg),
              acc[rt][ct], 0, 0, 0);
        }
      }
    }
  }
#pragma unroll
  for (int rt = 0; rt < 2; ++rt) {
    int r0 = rowBase + rt * 16 + lq * 4;
#pragma unroll
    for (int ct = 0; ct < 16; ++ct) {
      short* C = (ct < 8) ? C0 : C1;
      int col = (ct & 7) * 16 + l16;
#pragma unroll
      for (int r = 0; r < 4; ++r) {
        int row = r0 + r;
        if (row < M) C[(long)row * 128 + col] = f2b(acc[rt][ct][r]);
      }
    }
  }
}

// ---------------- scans ----------------
__global__ void scanA_k(const int* __restrict__ in, int* __restrict__ part,
                        int* __restrict__ bsums) {
  __shared__ int lds[256];
  int t = threadIdx.x, b = blockIdx.x;
  int base = b * 4096 + t * 16;
  int v[16];
  int run = 0;
#pragma unroll
  for (int j = 0; j < 16; ++j) {
    int x = (base + j < NNODES_) ? in[base + j] : 0;
    v[j] = run;
    run += x;
  }
  lds[t] = run;
  __syncthreads();
  int incl = run;
  for (int off = 1; off < 256; off <<= 1) {
    int add = (t >= off) ? lds[t - off] : 0;
    __syncthreads();
    lds[t] += add;
    incl = lds[t];
    __syncthreads();
  }
  int excl = incl - run;
#pragma unroll
  for (int j = 0; j < 16; ++j) part[base + j] = v[j] + excl;
  if (t == 255) bsums[b] = incl;
}
__global__ void scanB_k(int* __restrict__ bsums) {
  __shared__ int lds[256];
  int t = threadIdx.x;
  int v = (t < SCAN_BLOCKS_) ? bsums[t] : 0;
  lds[t] = v;
  __syncthreads();
  int incl = v;
  for (int off = 1; off < 256; off <<= 1) {
    int add = (t >= off) ? lds[t - off] : 0;
    __syncthreads();
    lds[t] += add;
    incl = lds[t];
    __syncthreads();
  }
  if (t < SCAN_BLOCKS_) bsums[t] = incl - v;
}
// scanC: finalize row_ptr + fused norms (dinv/invc from cnt)
__global__ void scanC_k(const int* __restrict__ part, const int* __restrict__ bsums,
                        const int* __restrict__ cnt, int* __restrict__ row_ptr,
                        float* __restrict__ dinv_aa, float* __restrict__ dinv_ss,
                        float* __restrict__ invc_sa) {
  int t = threadIdx.x, b = blockIdx.x;
  int base = b * 4096 + t * 16;
  int sb = bsums[b];
#pragma unroll
  for (int j = 0; j < 16; ++j) {
    int i = base + j;
    row_ptr[i] = part[i] + sb;
    if (i < NA_) dinv_aa[i] = rsqrtf((float)(cnt[i] + 1));
    else if (i < 2 * NA_) invc_sa[i - NA_] = 1.0f / fmaxf((float)cnt[i], 1.0f);
    else if (i < NNODES_) dinv_ss[i - 2 * NA_] = rsqrtf((float)(cnt[i] + 1));
  }
}

// ---------------- CSR pass 2: plain-store fill, 8B entries (src, weight) ----------------
__global__ void fill2_k(const int* __restrict__ src_aa, const int* __restrict__ dst_aa,
                        const int* __restrict__ sa_src, const int* __restrict__ sa_dst,
                        const int* __restrict__ src_ss, const int* __restrict__ dst_ss,
                        const int* __restrict__ row_ptr, const int* __restrict__ pos,
                        const float* __restrict__ dinv_aa, const float* __restrict__ dinv_ss,
                        const float* __restrict__ invc_sa, int2* __restrict__ pool) {
  int i = blockIdx.x * 256 + threadIdx.x;
  int s, node;
  float w;
  if (i < EAA_) {
    s = src_aa[i];
    int d = dst_aa[i];
    node = d;
    w = dinv_aa[s] * dinv_aa[d];
  } else if (i < EAA_ + ESA_) {
    int j = i - EAA_;
    s = sa_src[j];
    int d = sa_dst[j];
    node = NA_ + d;
    w = invc_sa[d];
  } else if (i < POOLE_) {
    int j = i - EAA_ - ESA_;
    s = src_ss[j];
    int d = dst_ss[j];
    node = 2 * NA_ + d;
    w = dinv_ss[s] * dinv_ss[d];
  } else
    return;
  pool[row_ptr[node] + pos[i]] = make_int2(s, __builtin_bit_cast(int, w));
}

// ---------------- gathers: 16 lanes/edge-row, short8 (16B) per lane ----------------
// Wave = 1 dst node. 4 groups of 16 lanes; group g walks edges jj+g, jj+4+g.
// Lane loads 8 contiguous bf16 channels (cb = (lane&15)*8) of its group's source row.
// Split loop: full 8-edge chunks run MASKLESS; one masked tail chunk handles the
// remainder. Byte-identical to the round-6-proven body.
static __device__ __forceinline__ void row_accum(const short* __restrict__ tab,
                                                 const int2* __restrict__ pool,
                                                 int r0, int r1, int g, int cb,
                                                 float* acc) {
  int n = r1 - r0;
  int r1f = r0 + (n & ~7);  // end of full (maskless) chunks
  for (int jj = r0; jj < r1f; jj += 8) {
    int2 p0 = pool[jj + g];
    int2 p1 = pool[jj + 4 + g];
    float w0 = __builtin_bit_cast(float, p0.y);
    float w1 = __builtin_bit_cast(float, p1.y);
    short8 v0 = *(const short8*)&tab[(long)p0.x * 128 + cb];
    short8 v1 = *(const short8*)&tab[(long)p1.x * 128 + cb];
#pragma unroll
    for (int j = 0; j < 8; ++j) {
      acc[j] += b2f(v0[j]) * w0;
      acc[j] += b2f(v1[j]) * w1;
    }
  }
  if (r1f < r1) {  // single masked tail chunk
    int e0 = r1f + g, e1 = r1f + 4 + g;
    int c0 = e0 < r1 ? e0 : r1 - 1;
    int c1 = e1 < r1 ? e1 : r1 - 1;
    int2 p0 = pool[c0];
    int2 p1 = pool[c1];
    float w0 = (e0 < r1) ? __builtin_bit_cast(float, p0.y) : 0.f;
    float w1 = (e1 < r1) ? __builtin_bit_cast(float, p1.y) : 0.f;
    short8 v0 = *(const short8*)&tab[(long)p0.x * 128 + cb];
    short8 v1 = *(const short8*)&tab[(long)p1.x * 128 + cb];
#pragma unroll
    for (int j = 0; j < 8; ++j) {
      acc[j] += b2f(v0[j]) * w0;
      acc[j] += b2f(v1[j]) * w1;
    }
  }
}

static __device__ __forceinline__ void xreduce8(float* acc) {
#pragma unroll
  for (int j = 0; j < 8; ++j) {
    acc[j] += __shfl_xor(acc[j], 16, 64);
    acc[j] += __shfl_xor(acc[j], 32, 64);
  }
}

// merged gather: blocks [0, NA_/4) -> article nodes, [NA_/4, NA_/4+NS_/4) -> software.
// NA_ and NS_ divisible by 4 -> the art/soft split is block-aligned (no wave divergence).
__global__ __launch_bounds__(256) void gather_all_k(
    const short* __restrict__ h_aa, const short* __restrict__ y_sl,
    const short* __restrict__ r_a, const short* __restrict__ h_ss,
    const int2* __restrict__ pool, const int* __restrict__ row_ptr,
    const float* __restrict__ dinv_aa, const float* __restrict__ dinv_ss,
    const float* __restrict__ b_aa, const float* __restrict__ b_sal,
    const float* __restrict__ b_ss, float* __restrict__ out_art,
    float* __restrict__ out_soft) {
  int wave = threadIdx.x >> 6, lane = threadIdx.x & 63;
  int node = blockIdx.x * 4 + wave;
  int l16 = lane & 15, g = lane >> 4;
  int cb = l16 * 8;

  if (node < NA_) {
    int d = node;
    float accA[8], accS[8];
#pragma unroll
    for (int j = 0; j < 8; ++j) accA[j] = accS[j] = 0.f;

    // GCN aa neighbors (weight = dinv[s]*dinv[d], precomputed)
    row_accum(h_aa, pool, row_ptr[d], row_ptr[d + 1], g, cb, accA);
    // SAGE sa neighbors (weight = invc[d], precomputed -> sum is already the mean)
    row_accum(y_sl, pool, row_ptr[NA_ + d], row_ptr[NA_ + d + 1], g, cb, accS);
    xreduce8(accA);
    xreduce8(accS);

    if (g == 0) {
      float dd = dinv_aa[d];
      float d2 = dd * dd;
      short8 hv = *(const short8*)&h_aa[(long)d * 128 + cb];
      short8 rv = *(const short8*)&r_a[(long)d * 128 + cb];
      float4v ba0 = *(const float4v*)&b_aa[cb];
      float4v ba1 = *(const float4v*)&b_aa[cb + 4];
      float4v bl0 = *(const float4v*)&b_sal[cb];
      float4v bl1 = *(const float4v*)&b_sal[cb + 4];
      float4v o0, o1;
#pragma unroll
      for (int j = 0; j < 4; ++j) {
        float t0 =
            0.5f * ((accA[j] + b2f(hv[j]) * d2 + ba0[j]) + (accS[j] + bl0[j] + b2f(rv[j])));
        float t1 = 0.5f * ((accA[4 + j] + b2f(hv[4 + j]) * d2 + ba1[j]) +
                           (accS[4 + j] + bl1[j] + b2f(rv[4 + j])));
        o0[j] = fmaxf(t0, 0.f);
        o1[j] = fmaxf(t1, 0.f);
      }
      *(float4v*)&out_art[(long)d * 128 + cb] = o0;
      *(float4v*)&out_art[(long)d * 128 + cb + 4] = o1;
    }
  } else {
    int d = node - NA_;
    if (d >= NS_) return;
    float acc[8];
#pragma unroll
    for (int j = 0; j < 8; ++j) acc[j] = 0.f;
    row_accum(h_ss, pool, row_ptr[2 * NA_ + d], row_ptr[2 * NA_ + d + 1], g, cb, acc);
    xreduce8(acc);

    if (g == 0) {
      float dd = dinv_ss[d];
      float d2 = dd * dd;
      short8 hv = *(const short8*)&h_ss[(long)d * 128 + cb];
      float4v bs0 = *(const float4v*)&b_ss[cb];
      float4v bs1 = *(const float4v*)&b_ss[cb + 4];
      float4v o0, o1;
#pragma unroll
      for (int j = 0; j < 4; ++j) {
        o0[j] = fmaxf(acc[j] + b2f(hv[j]) * d2 + bs0[j], 0.f);
        o1[j] = fmaxf(acc[4 + j] + b2f(hv[4 + j]) * d2 + bs1[j], 0.f);
      }
      *(float4v*)&out_soft[(long)d * 128 + cb] = o0;
      *(float4v*)&out_soft[(long)d * 128 + cb + 4] = o1;
    }
  }
}

extern "C" void kernel_launch(void* const* d_in, const int* in_sizes, int n_in,
                              void* d_out, int out_size, void* d_ws, size_t ws_size,
                              hipStream_t stream) {
  const float* x_a = (const float*)d_in[0];
  const float* x_s = (const float*)d_in[1];
  const int* ei_aa = (const int*)d_in[2];
  const int* ei_ss = (const int*)d_in[3];
  const int* sa_src = (const int*)d_in[4];
  const int* sa_dst = (const int*)d_in[5];
  const float* W_aa = (const float*)d_in[6];
  const float* b_aa = (const float*)d_in[7];
  const float* W_ss = (const float*)d_in[8];
  const float* b_ss = (const float*)d_in[9];
  const float* W_sal = (const float*)d_in[10];
  const float* b_sal = (const float*)d_in[11];
  const float* W_sar = (const float*)d_in[12];

  const int* src_aa = ei_aa;
  const int* dst_aa = ei_aa + EAA_;
  const int* src_ss = ei_ss;
  const int* dst_ss = ei_ss + ESS_;

  // ---- workspace (~180 MB, identical layout to the proven round-3/6 runs) ----
  char* base = (char*)d_ws;
  size_t off = 0;
  auto alloc = [&](size_t bytes) {
    void* p = base + off;
    off += (bytes + 511) & ~(size_t)511;
    return p;
  };
  short* xb_a = (short*)alloc((size_t)NA_ * 256 * 2);   // 51.2 MB
  short* xb_s = (short*)alloc((size_t)NS_ * 256 * 2);   // 25.6 MB
  short* h_aa = (short*)alloc((size_t)NA_ * 128 * 2);   // 25.6 MB
  short* h_ss = (short*)alloc((size_t)NS_ * 128 * 2);   // 12.8 MB
  short* y_sl = (short*)alloc((size_t)NS_ * 128 * 2);   // 12.8 MB
  short* r_a = (short*)alloc((size_t)NA_ * 128 * 2);    // 25.6 MB
  int2* pool = (int2*)alloc((size_t)POOLE_ * 8);        // 16 MB
  int* pos = (int*)alloc((size_t)POOLE_ * 4);           // 8 MB
  int* cnt_all = (int*)alloc((size_t)NNODES_ * 4);
  int* part = (int*)alloc((size_t)NPAD_ * 4);
  int* row_ptr = (int*)alloc((size_t)NPAD_ * 4);
  int* bsums = (int*)alloc(256 * 4);
  float* dinv_aa = (float*)alloc((size_t)NA_ * 4);
  float* dinv_ss = (float*)alloc((size_t)NS_ * 4);
  float* invc_sa = (float*)alloc((size_t)NA_ * 4);
  short* Wt_aa = (short*)alloc(128 * 256 * 2);
  short* Wt_ss = (short*)alloc(128 * 256 * 2);
  short* Wt_sal = (short*)alloc(128 * 256 * 2);
  short* Wt_sar = (short*)alloc(128 * 256 * 2);

  float* out_art = (float*)d_out;
  float* out_soft = (float*)d_out + (size_t)NA_ * 128;

  // ---- fused prep: count_pos + cvt_a + cvt_s + transposes (one launch) ----
  hipMemsetAsync(cnt_all, 0, (size_t)NNODES_ * 4, stream);
  prep_k<<<PREPB_, 256, 0, stream>>>(dst_aa, sa_dst, dst_ss, cnt_all, pos, x_a, xb_a, x_s,
                                     xb_s, W_aa, W_ss, W_sal, W_sar, Wt_aa, Wt_ss, Wt_sal,
                                     Wt_sar);

  // ---- scans + CSR fill ----
  scanA_k<<<SCAN_BLOCKS_, 256, 0, stream>>>(cnt_all, part, bsums);
  scanB_k<<<1, 256, 0, stream>>>(bsums);
  scanC_k<<<SCAN_BLOCKS_, 256, 0, stream>>>(part, bsums, cnt_all, row_ptr, dinv_aa, dinv_ss,
                                            invc_sa);
  fill2_k<<<(POOLE_ + 255) / 256, 256, 0, stream>>>(src_aa, dst_aa, sa_src, sa_dst, src_ss,
                                                    dst_ss, row_ptr, pos, dinv_aa, dinv_ss,
                                                    invc_sa, pool);

  // ---- fused GEMMs ----
  gemm2_k<<<(NA_ + 127) / 128, 256, 0, stream>>>(xb_a, Wt_aa, Wt_sar, h_aa, r_a, NA_);
  gemm2_k<<<(NS_ + 127) / 128, 256, 0, stream>>>(xb_s, Wt_ss, Wt_sal, h_ss, y_sl, NS_);

  // ---- merged gather (art blocks 0..24999, soft blocks 25000..37499) ----
  gather_all_k<<<(NA_ + NS_) / 4, 256, 0, stream>>>(h_aa, y_sl, r_a, h_ss, pool, row_ptr,
                                                    dinv_aa, dinv_ss, b_aa, b_sal, b_ss,
                                                    out_art, out_soft);
}

// Round 8
// 539.457 us; speedup vs baseline: 1.1917x; 1.1027x over previous
//
#include <hip/hip_runtime.h>

typedef short short8 __attribute__((ext_vector_type(8)));
typedef float float4v __attribute__((ext_vector_type(4)));
typedef __bf16 bf16x8 __attribute__((ext_vector_type(8)));

#define NA_ 100000
#define NS_ 50000
#define EAA_ 800000
#define ESS_ 400000
#define ESA_ 800000
#define POOLE_ (EAA_ + ESA_ + ESS_)  // 2,000,000
// concatenated node index space: [aa: 0..NA_), [sa: NA_..2*NA_), [ss: 2*NA_..2*NA_+NS_)
#define NNODES_ (NA_ + NA_ + NS_)   // 250000
#define SCAN_BLOCKS_ 62             // 62*4096 = 253952 >= NNODES_+1
#define NPAD_ (SCAN_BLOCKS_ * 4096)

// prep_k block-range layout (all 256-thread, LDS-free).
// Count blocks: 489 blocks x 4096 edges (16/thread, unrolled -> 16 outstanding atomics
// per thread). Small block count leaves ~76% of resident-block slots for the streaming
// cvt/transpose blocks, so their ~60us of HBM work hides under the ~87us atomic drain
// (round-7 lesson: 7813 one-shot count blocks stalled the whole machine -> additive time).
#define CPB_ 489     // 489*4096 = 2,002,944 >= POOLE_
#define CVA_ 12500   // cvt x_article: 12500*256 = NA_*32 exactly
#define CVS_ 6250    // cvt x_software: 6250*256 = NS_*32 exactly
#define TRB_ 512     // transpose: 512*256 = 4*32768 exactly
#define PREPB_ (CPB_ + CVA_ + CVS_ + TRB_)

static __device__ __forceinline__ float b2f(short s) {
  unsigned int u = ((unsigned int)(unsigned short)s) << 16;
  return __builtin_bit_cast(float, u);
}
static __device__ __forceinline__ short f2b(float f) {
  unsigned int u = __builtin_bit_cast(unsigned int, f);
  u = u + 0x7FFFu + ((u >> 16) & 1u);
  return (short)(u >> 16);
}

// bf16 convert: 8 floats -> 8 shorts at element index i*8
static __device__ __forceinline__ void cvt_body(const float* __restrict__ x,
                                                short* __restrict__ y, int i) {
  const float* xp = x + (long)i * 8;
  float4v a0 = *(const float4v*)xp;
  float4v a1 = *(const float4v*)(xp + 4);
  short8 r;
#pragma unroll
  for (int j = 0; j < 4; ++j) {
    r[j] = f2b(a0[j]);
    r[4 + j] = f2b(a1[j]);
  }
  *(short8*)&y[(long)i * 8] = r;
}

// ---------------- fused prep: count_pos + cvt_a + cvt_s + 4x W transpose ----------------
__global__ __launch_bounds__(256) void prep_k(
    const int* __restrict__ dst_aa, const int* __restrict__ sa_dst,
    const int* __restrict__ dst_ss, int* __restrict__ cnt, int* __restrict__ pos,
    const float* __restrict__ x_a, short* __restrict__ xb_a,
    const float* __restrict__ x_s, short* __restrict__ xb_s,
    const float* __restrict__ W0, const float* __restrict__ W1,
    const float* __restrict__ W2, const float* __restrict__ W3,
    short* __restrict__ T0, short* __restrict__ T1,
    short* __restrict__ T2, short* __restrict__ T3) {
  int b = blockIdx.x, t = threadIdx.x;
  if (b < CPB_) {
    int base = b * 4096 + t;
#pragma unroll
    for (int it = 0; it < 16; ++it) {
      int i = base + it * 256;  // coalesced per iteration
      if (i < POOLE_) {
        int node;
        if (i < EAA_) node = dst_aa[i];
        else if (i < EAA_ + ESA_) node = NA_ + sa_dst[i - EAA_];
        else node = 2 * NA_ + dst_ss[i - EAA_ - ESA_];
        pos[i] = atomicAdd(&cnt[node], 1);
      }
    }
  } else if (b < CPB_ + CVA_) {
    cvt_body(x_a, xb_a, (b - CPB_) * 256 + t);
  } else if (b < CPB_ + CVA_ + CVS_) {
    cvt_body(x_s, xb_s, (b - CPB_ - CVA_) * 256 + t);
  } else {
    int tid = (b - CPB_ - CVA_ - CVS_) * 256 + t;  // 0 .. 4*32768
    int which = tid >> 15, r = tid & 32767;
    const float* W = which == 0 ? W0 : which == 1 ? W1 : which == 2 ? W2 : W3;
    short* T = which == 0 ? T0 : which == 1 ? T1 : which == 2 ? T2 : T3;
    int k = r >> 7, n = r & 127;
    T[n * 256 + k] = f2b(W[k * 128 + n]);
  }
}

// ---------------- fused dual GEMM: C0,C1[M,128] = A[M,256] @ {Wt0,Wt1}^T ----------------
// A bf16 row-major; Wt0/Wt1 bf16 [128][256]. Block = 256 thr = 4 waves x 32 rows = 128 rows.
// LDS: 256 stacked N-rows (128 per weight) x 64-K-tile, stride 72 shorts (144B = 36 dw,
// 36 mod 32 = 4 -> 2-way bank alias = free, same pattern as proven LDN=136).
#define LDK 72
__global__ __launch_bounds__(256) void gemm2_k(const short* __restrict__ A,
                                               const short* __restrict__ Wt0,
                                               const short* __restrict__ Wt1,
                                               short* __restrict__ C0,
                                               short* __restrict__ C1, int M) {
  __shared__ short lds[256 * LDK];
  int tid = threadIdx.x;
  int wave = tid >> 6, lane = tid & 63;
  int l16 = lane & 15, lq = lane >> 4;
  int rowBase = blockIdx.x * 128 + wave * 32;

  float4v acc[2][16];
#pragma unroll
  for (int rt = 0; rt < 2; ++rt)
#pragma unroll
    for (int ct = 0; ct < 16; ++ct) acc[rt][ct] = (float4v){0.f, 0.f, 0.f, 0.f};

  for (int p = 0; p < 4; ++p) {
    int kp = p * 64;
    __syncthreads();
    // stage both weights' K-slice [*, kp:kp+64] into LDS (2048 short8 chunks)
    for (int idx = tid; idx < 2048; idx += 256) {
      int row = idx >> 3, c = idx & 7;  // row 0..255, c 0..7
      const short* Wsrc = (row < 128) ? &Wt0[row * 256] : &Wt1[(row - 128) * 256];
      *(short8*)&lds[row * LDK + c * 8] = *(const short8*)&Wsrc[kp + c * 8];
    }
    __syncthreads();
#pragma unroll
    for (int ks = 0; ks < 2; ++ks) {
      int k0 = kp + ks * 32;
      short8 af[2];
#pragma unroll
      for (int rt = 0; rt < 2; ++rt) {
        int row = rowBase + rt * 16 + l16;
        if (row >= M) row = M - 1;
        af[rt] = *(const short8*)&A[(long)row * 256 + k0 + lq * 8];
      }
#pragma unroll
      for (int ct = 0; ct < 16; ++ct) {
        short8 bfg = *(const short8*)&lds[(ct * 16 + l16) * LDK + ks * 32 + lq * 8];
#pragma unroll
        for (int rt = 0; rt < 2; ++rt) {
          acc[rt][ct] = __builtin_amdgcn_mfma_f32_16x16x32_bf16(
              __builtin_bit_cast(bf16x8, af[rt]), __builtin_bit_cast(bf16x8, bfg),
              acc[rt][ct], 0, 0, 0);
        }
      }
    }
  }
#pragma unroll
  for (int rt = 0; rt < 2; ++rt) {
    int r0 = rowBase + rt * 16 + lq * 4;
#pragma unroll
    for (int ct = 0; ct < 16; ++ct) {
      short* C = (ct < 8) ? C0 : C1;
      int col = (ct & 7) * 16 + l16;
#pragma unroll
      for (int r = 0; r < 4; ++r) {
        int row = r0 + r;
        if (row < M) C[(long)row * 128 + col] = f2b(acc[rt][ct][r]);
      }
    }
  }
}

// ---------------- scans ----------------
__global__ void scanA_k(const int* __restrict__ in, int* __restrict__ part,
                        int* __restrict__ bsums) {
  __shared__ int lds[256];
  int t = threadIdx.x, b = blockIdx.x;
  int base = b * 4096 + t * 16;
  int v[16];
  int run = 0;
#pragma unroll
  for (int j = 0; j < 16; ++j) {
    int x = (base + j < NNODES_) ? in[base + j] : 0;
    v[j] = run;
    run += x;
  }
  lds[t] = run;
  __syncthreads();
  int incl = run;
  for (int off = 1; off < 256; off <<= 1) {
    int add = (t >= off) ? lds[t - off] : 0;
    __syncthreads();
    lds[t] += add;
    incl = lds[t];
    __syncthreads();
  }
  int excl = incl - run;
#pragma unroll
  for (int j = 0; j < 16; ++j) part[base + j] = v[j] + excl;
  if (t == 255) bsums[b] = incl;
}
__global__ void scanB_k(int* __restrict__ bsums) {
  __shared__ int lds[256];
  int t = threadIdx.x;
  int v = (t < SCAN_BLOCKS_) ? bsums[t] : 0;
  lds[t] = v;
  __syncthreads();
  int incl = v;
  for (int off = 1; off < 256; off <<= 1) {
    int add = (t >= off) ? lds[t - off] : 0;
    __syncthreads();
    lds[t] += add;
    incl = lds[t];
    __syncthreads();
  }
  if (t < SCAN_BLOCKS_) bsums[t] = incl - v;
}
// scanC: finalize row_ptr + fused norms (dinv/invc from cnt)
__global__ void scanC_k(const int* __restrict__ part, const int* __restrict__ bsums,
                        const int* __restrict__ cnt, int* __restrict__ row_ptr,
                        float* __restrict__ dinv_aa, float* __restrict__ dinv_ss,
                        float* __restrict__ invc_sa) {
  int t = threadIdx.x, b = blockIdx.x;
  int base = b * 4096 + t * 16;
  int sb = bsums[b];
#pragma unroll
  for (int j = 0; j < 16; ++j) {
    int i = base + j;
    row_ptr[i] = part[i] + sb;
    if (i < NA_) dinv_aa[i] = rsqrtf((float)(cnt[i] + 1));
    else if (i < 2 * NA_) invc_sa[i - NA_] = 1.0f / fmaxf((float)cnt[i], 1.0f);
    else if (i < NNODES_) dinv_ss[i - 2 * NA_] = rsqrtf((float)(cnt[i] + 1));
  }
}

// ---------------- CSR pass 2: plain-store fill, 8B entries (src, weight) ----------------
__global__ void fill2_k(const int* __restrict__ src_aa, const int* __restrict__ dst_aa,
                        const int* __restrict__ sa_src, const int* __restrict__ sa_dst,
                        const int* __restrict__ src_ss, const int* __restrict__ dst_ss,
                        const int* __restrict__ row_ptr, const int* __restrict__ pos,
                        const float* __restrict__ dinv_aa, const float* __restrict__ dinv_ss,
                        const float* __restrict__ invc_sa, int2* __restrict__ pool) {
  int i = blockIdx.x * 256 + threadIdx.x;
  int s, node;
  float w;
  if (i < EAA_) {
    s = src_aa[i];
    int d = dst_aa[i];
    node = d;
    w = dinv_aa[s] * dinv_aa[d];
  } else if (i < EAA_ + ESA_) {
    int j = i - EAA_;
    s = sa_src[j];
    int d = sa_dst[j];
    node = NA_ + d;
    w = invc_sa[d];
  } else if (i < POOLE_) {
    int j = i - EAA_ - ESA_;
    s = src_ss[j];
    int d = dst_ss[j];
    node = 2 * NA_ + d;
    w = dinv_ss[s] * dinv_ss[d];
  } else
    return;
  pool[row_ptr[node] + pos[i]] = make_int2(s, __builtin_bit_cast(int, w));
}

// ---------------- gathers: 16 lanes/edge-row, short8 (16B) per lane ----------------
// Wave = 1 dst node. 4 groups of 16 lanes; group g walks edges jj+g, jj+4+g.
// Lane loads 8 contiguous bf16 channels (cb = (lane&15)*8) of its group's source row.
// Split loop: full 8-edge chunks run MASKLESS; one masked tail chunk handles the
// remainder. Byte-identical to the round-6-proven body.
static __device__ __forceinline__ void row_accum(const short* __restrict__ tab,
                                                 const int2* __restrict__ pool,
                                                 int r0, int r1, int g, int cb,
                                                 float* acc) {
  int n = r1 - r0;
  int r1f = r0 + (n & ~7);  // end of full (maskless) chunks
  for (int jj = r0; jj < r1f; jj += 8) {
    int2 p0 = pool[jj + g];
    int2 p1 = pool[jj + 4 + g];
    float w0 = __builtin_bit_cast(float, p0.y);
    float w1 = __builtin_bit_cast(float, p1.y);
    short8 v0 = *(const short8*)&tab[(long)p0.x * 128 + cb];
    short8 v1 = *(const short8*)&tab[(long)p1.x * 128 + cb];
#pragma unroll
    for (int j = 0; j < 8; ++j) {
      acc[j] += b2f(v0[j]) * w0;
      acc[j] += b2f(v1[j]) * w1;
    }
  }
  if (r1f < r1) {  // single masked tail chunk
    int e0 = r1f + g, e1 = r1f + 4 + g;
    int c0 = e0 < r1 ? e0 : r1 - 1;
    int c1 = e1 < r1 ? e1 : r1 - 1;
    int2 p0 = pool[c0];
    int2 p1 = pool[c1];
    float w0 = (e0 < r1) ? __builtin_bit_cast(float, p0.y) : 0.f;
    float w1 = (e1 < r1) ? __builtin_bit_cast(float, p1.y) : 0.f;
    short8 v0 = *(const short8*)&tab[(long)p0.x * 128 + cb];
    short8 v1 = *(const short8*)&tab[(long)p1.x * 128 + cb];
#pragma unroll
    for (int j = 0; j < 8; ++j) {
      acc[j] += b2f(v0[j]) * w0;
      acc[j] += b2f(v1[j]) * w1;
    }
  }
}

static __device__ __forceinline__ void xreduce8(float* acc) {
#pragma unroll
  for (int j = 0; j < 8; ++j) {
    acc[j] += __shfl_xor(acc[j], 16, 64);
    acc[j] += __shfl_xor(acc[j], 32, 64);
  }
}

// merged gather: blocks [0, NA_/4) -> article nodes, [NA_/4, NA_/4+NS_/4) -> software.
// NA_ and NS_ divisible by 4 -> the art/soft split is block-aligned (no wave divergence).
__global__ __launch_bounds__(256) void gather_all_k(
    const short* __restrict__ h_aa, const short* __restrict__ y_sl,
    const short* __restrict__ r_a, const short* __restrict__ h_ss,
    const int2* __restrict__ pool, const int* __restrict__ row_ptr,
    const float* __restrict__ dinv_aa, const float* __restrict__ dinv_ss,
    const float* __restrict__ b_aa, const float* __restrict__ b_sal,
    const float* __restrict__ b_ss, float* __restrict__ out_art,
    float* __restrict__ out_soft) {
  int wave = threadIdx.x >> 6, lane = threadIdx.x & 63;
  int node = blockIdx.x * 4 + wave;
  int l16 = lane & 15, g = lane >> 4;
  int cb = l16 * 8;

  if (node < NA_) {
    int d = node;
    float accA[8], accS[8];
#pragma unroll
    for (int j = 0; j < 8; ++j) accA[j] = accS[j] = 0.f;

    // GCN aa neighbors (weight = dinv[s]*dinv[d], precomputed)
    row_accum(h_aa, pool, row_ptr[d], row_ptr[d + 1], g, cb, accA);
    // SAGE sa neighbors (weight = invc[d], precomputed -> sum is already the mean)
    row_accum(y_sl, pool, row_ptr[NA_ + d], row_ptr[NA_ + d + 1], g, cb, accS);
    xreduce8(accA);
    xreduce8(accS);

    if (g == 0) {
      float dd = dinv_aa[d];
      float d2 = dd * dd;
      short8 hv = *(const short8*)&h_aa[(long)d * 128 + cb];
      short8 rv = *(const short8*)&r_a[(long)d * 128 + cb];
      float4v ba0 = *(const float4v*)&b_aa[cb];
      float4v ba1 = *(const float4v*)&b_aa[cb + 4];
      float4v bl0 = *(const float4v*)&b_sal[cb];
      float4v bl1 = *(const float4v*)&b_sal[cb + 4];
      float4v o0, o1;
#pragma unroll
      for (int j = 0; j < 4; ++j) {
        float t0 =
            0.5f * ((accA[j] + b2f(hv[j]) * d2 + ba0[j]) + (accS[j] + bl0[j] + b2f(rv[j])));
        float t1 = 0.5f * ((accA[4 + j] + b2f(hv[4 + j]) * d2 + ba1[j]) +
                           (accS[4 + j] + bl1[j] + b2f(rv[4 + j])));
        o0[j] = fmaxf(t0, 0.f);
        o1[j] = fmaxf(t1, 0.f);
      }
      *(float4v*)&out_art[(long)d * 128 + cb] = o0;
      *(float4v*)&out_art[(long)d * 128 + cb + 4] = o1;
    }
  } else {
    int d = node - NA_;
    if (d >= NS_) return;
    float acc[8];
#pragma unroll
    for (int j = 0; j < 8; ++j) acc[j] = 0.f;
    row_accum(h_ss, pool, row_ptr[2 * NA_ + d], row_ptr[2 * NA_ + d + 1], g, cb, acc);
    xreduce8(acc);

    if (g == 0) {
      float dd = dinv_ss[d];
      float d2 = dd * dd;
      short8 hv = *(const short8*)&h_ss[(long)d * 128 + cb];
      float4v bs0 = *(const float4v*)&b_ss[cb];
      float4v bs1 = *(const float4v*)&b_ss[cb + 4];
      float4v o0, o1;
#pragma unroll
      for (int j = 0; j < 4; ++j) {
        o0[j] = fmaxf(acc[j] + b2f(hv[j]) * d2 + bs0[j], 0.f);
        o1[j] = fmaxf(acc[4 + j] + b2f(hv[4 + j]) * d2 + bs1[j], 0.f);
      }
      *(float4v*)&out_soft[(long)d * 128 + cb] = o0;
      *(float4v*)&out_soft[(long)d * 128 + cb + 4] = o1;
    }
  }
}

extern "C" void kernel_launch(void* const* d_in, const int* in_sizes, int n_in,
                              void* d_out, int out_size, void* d_ws, size_t ws_size,
                              hipStream_t stream) {
  const float* x_a = (const float*)d_in[0];
  const float* x_s = (const float*)d_in[1];
  const int* ei_aa = (const int*)d_in[2];
  const int* ei_ss = (const int*)d_in[3];
  const int* sa_src = (const int*)d_in[4];
  const int* sa_dst = (const int*)d_in[5];
  const float* W_aa = (const float*)d_in[6];
  const float* b_aa = (const float*)d_in[7];
  const float* W_ss = (const float*)d_in[8];
  const float* b_ss = (const float*)d_in[9];
  const float* W_sal = (const float*)d_in[10];
  const float* b_sal = (const float*)d_in[11];
  const float* W_sar = (const float*)d_in[12];

  const int* src_aa = ei_aa;
  const int* dst_aa = ei_aa + EAA_;
  const int* src_ss = ei_ss;
  const int* dst_ss = ei_ss + ESS_;

  // ---- workspace (~180 MB, identical layout to the proven round-3/6/7 runs) ----
  char* base = (char*)d_ws;
  size_t off = 0;
  auto alloc = [&](size_t bytes) {
    void* p = base + off;
    off += (bytes + 511) & ~(size_t)511;
    return p;
  };
  short* xb_a = (short*)alloc((size_t)NA_ * 256 * 2);   // 51.2 MB
  short* xb_s = (short*)alloc((size_t)NS_ * 256 * 2);   // 25.6 MB
  short* h_aa = (short*)alloc((size_t)NA_ * 128 * 2);   // 25.6 MB
  short* h_ss = (short*)alloc((size_t)NS_ * 128 * 2);   // 12.8 MB
  short* y_sl = (short*)alloc((size_t)NS_ * 128 * 2);   // 12.8 MB
  short* r_a = (short*)alloc((size_t)NA_ * 128 * 2);    // 25.6 MB
  int2* pool = (int2*)alloc((size_t)POOLE_ * 8);        // 16 MB
  int* pos = (int*)alloc((size_t)POOLE_ * 4);           // 8 MB
  int* cnt_all = (int*)alloc((size_t)NNODES_ * 4);
  int* part = (int*)alloc((size_t)NPAD_ * 4);
  int* row_ptr = (int*)alloc((size_t)NPAD_ * 4);
  int* bsums = (int*)alloc(256 * 4);
  float* dinv_aa = (float*)alloc((size_t)NA_ * 4);
  float* dinv_ss = (float*)alloc((size_t)NS_ * 4);
  float* invc_sa = (float*)alloc((size_t)NA_ * 4);
  short* Wt_aa = (short*)alloc(128 * 256 * 2);
  short* Wt_ss = (short*)alloc(128 * 256 * 2);
  short* Wt_sal = (short*)alloc(128 * 256 * 2);
  short* Wt_sar = (short*)alloc(128 * 256 * 2);

  float* out_art = (float*)d_out;
  float* out_soft = (float*)d_out + (size_t)NA_ * 128;

  // ---- fused prep: count_pos (489 deep blocks) + cvt_a + cvt_s + transposes ----
  hipMemsetAsync(cnt_all, 0, (size_t)NNODES_ * 4, stream);
  prep_k<<<PREPB_, 256, 0, stream>>>(dst_aa, sa_dst, dst_ss, cnt_all, pos, x_a, xb_a, x_s,
                                     xb_s, W_aa, W_ss, W_sal, W_sar, Wt_aa, Wt_ss, Wt_sal,
                                     Wt_sar);

  // ---- scans + CSR fill ----
  scanA_k<<<SCAN_BLOCKS_, 256, 0, stream>>>(cnt_all, part, bsums);
  scanB_k<<<1, 256, 0, stream>>>(bsums);
  scanC_k<<<SCAN_BLOCKS_, 256, 0, stream>>>(part, bsums, cnt_all, row_ptr, dinv_aa, dinv_ss,
                                            invc_sa);
  fill2_k<<<(POOLE_ + 255) / 256, 256, 0, stream>>>(src_aa, dst_aa, sa_src, sa_dst, src_ss,
                                                    dst_ss, row_ptr, pos, dinv_aa, dinv_ss,
                                                    invc_sa, pool);

  // ---- fused GEMMs ----
  gemm2_k<<<(NA_ + 127) / 128, 256, 0, stream>>>(xb_a, Wt_aa, Wt_sar, h_aa, r_a, NA_);
  gemm2_k<<<(NS_ + 127) / 128, 256, 0, stream>>>(xb_s, Wt_ss, Wt_sal, h_ss, y_sl, NS_);

  // ---- merged gather (art blocks 0..24999, soft blocks 25000..37499) ----
  gather_all_k<<<(NA_ + NS_) / 4, 256, 0, stream>>>(h_aa, y_sl, r_a, h_ss, pool, row_ptr,
                                                    dinv_aa, dinv_ss, b_aa, b_sal, b_ss,
                                                    out_art, out_soft);
}